// Round 10
// baseline (224.080 us; speedup 1.0000x reference)
//
#include <hip/hip_runtime.h>
#include <hip/hip_bf16.h>
#include <stdint.h>

#define BATCH 4
#define SEQ   2048
#define EMB   1024
#define ADIM  1024

typedef __attribute__((ext_vector_type(8))) short  short8;
typedef __attribute__((ext_vector_type(4))) float  float4v;

static __device__ __forceinline__ unsigned short f2bf(float f) {
    unsigned int u = __float_as_uint(f);
    u += 0x7FFFu + ((u >> 16) & 1u);   // RNE (finite inputs)
    return (unsigned short)(u >> 16);
}

static __device__ __forceinline__ uint2 pack4(float4v v) {
    uint2 r;
    r.x = (unsigned)f2bf(v.x) | ((unsigned)f2bf(v.y) << 16);
    r.y = (unsigned)f2bf(v.z) | ((unsigned)f2bf(v.w) << 16);
    return r;
}

// async global->LDS, 16B per lane. LDS dest is wave-uniform base + lane*16.
static __device__ __forceinline__ void gload16(const void* g, void* l) {
    __builtin_amdgcn_global_load_lds(
        (const __attribute__((address_space(1))) void*)g,
        (__attribute__((address_space(3))) void*)l, 16, 0, 0);
}

// bank swizzle for 64B LDS rows (element-unit XOR for 8-el/16B accesses)
static __device__ __forceinline__ int swz8(int row) { return ((row >> 1) & 3) << 3; }

// ---- fused prep: X->Xb, Wv->Wvb, zero rowsum, transpose-convert Wq/Wk ----
__global__ __launch_bounds__(256) void prep_kernel(
    const float* __restrict__ X,  const float* __restrict__ Wv,
    const float* __restrict__ Wq, const float* __restrict__ Wk,
    unsigned short* __restrict__ Xb, unsigned short* __restrict__ Wvb,
    unsigned short* __restrict__ WqT, unsigned short* __restrict__ WkT,
    float* __restrict__ rowsum)
{
    __shared__ unsigned short T[64][72];
    const int bI = blockIdx.x;
    if (bI < 4608) {              // straight convert
        const float* src; unsigned short* dst; int off;
        if (bI < 4096) { src = X;  dst = Xb;  off = bI; }
        else           { src = Wv; dst = Wvb; off = bI - 4096; }
        const int i = (off * 256 + threadIdx.x) * 8;
        float4v a = *(const float4v*)(src + i);
        float4v b = *(const float4v*)(src + i + 4);
        uint2 pa = pack4(a), pb = pack4(b);
        uint4 o; o.x = pa.x; o.y = pa.y; o.z = pb.x; o.w = pb.y;
        *(uint4*)(dst + i) = o;
        return;
    }
    if (bI < 4616) {              // zero 32 KB rowsum
        const int i = ((bI - 4608) * 256 + threadIdx.x) * 4;
        *(float4v*)(rowsum + i) = float4v{0.f, 0.f, 0.f, 0.f};
        return;
    }
    // transpose-convert: W fp32 [a][e] -> WT bf16 [e][a], 64x64 tiles
    const int z    = (bI - 4616) >> 8;     // 0: Wq, 1: Wk
    const int tile = (bI - 4616) & 255;
    const int ti = tile >> 4;              // a-tile
    const int tj = tile & 15;              // e-tile
    const float* W = z ? Wk : Wq;
    unsigned short* WT = z ? WkT : WqT;
    const int t  = threadIdx.x;
    const int r  = t >> 2;                 // 0..63
    const int c  = (t & 3) << 4;           // 0,16,32,48

    const float* src = W + (size_t)(ti * 64 + r) * EMB + tj * 64 + c;
    #pragma unroll
    for (int u = 0; u < 4; ++u) {
        float4v v = *(const float4v*)(src + 4 * u);
        uint2 p = pack4(v);
        *(uint2*)&T[r][c + 4 * u] = p;
    }
    __syncthreads();
    unsigned short tmp[16];
    #pragma unroll
    for (int u = 0; u < 16; ++u) tmp[u] = T[c + u][r];
    unsigned short* dst = WT + (size_t)(tj * 64 + r) * EMB + ti * 64 + c;
    *(uint4*)(dst)     = *(uint4*)&tmp[0];
    *(uint4*)(dst + 8) = *(uint4*)&tmp[8];
}

// ---- 128x128 core: 3-stage pipeline, BK=32/stage, vmcnt(8), raw barriers.
// LDS bank-swizzled both sides (source-swizzled gload + XOR'd ds_read). ----
static __device__ __forceinline__ void gemm_core(
    const unsigned short* __restrict__ A, const unsigned short* __restrict__ B,
    int lda, int ldb, int m0, int n0, int klen,
    unsigned short* As, unsigned short* Bs, float4v acc[4][4])
{
    const int tid  = threadIdx.x;
    const int r    = tid >> 2;
    const int c8   = ((tid & 3) << 3) ^ swz8(tid >> 2);   // source-swizzled
    const int lane = tid & 63;
    const int wave = tid >> 6;
    const int quad = lane >> 4;
    const int l16  = lane & 15;
    const int wm   = (wave >> 1) << 6;
    const int wn   = (wave & 1) << 6;

    const unsigned short* Ag = A + (size_t)(m0 + r) * lda + c8;
    const unsigned short* Bg = B + (size_t)(n0 + r) * ldb + c8;
    unsigned short* Al = As + tid * 8;
    unsigned short* Bl = Bs + tid * 8;
    const int niter = klen >> 5;

    #define ISSUE(k0, st) do { \
        unsigned short* al_ = Al + (st) * 4096; \
        unsigned short* bl_ = Bl + (st) * 4096; \
        gload16(Ag + (k0),                    al_); \
        gload16(Ag + (k0) + (size_t)64 * lda, al_ + 2048); \
        gload16(Bg + (k0),                    bl_); \
        gload16(Bg + (k0) + (size_t)64 * ldb, bl_ + 2048); \
    } while (0)

    ISSUE(0, 0);
    ISSUE(32, 1);

    int ci = 0, ii = 2;
    for (int it = 0; it < niter; ++it) {
        const int knext = (it + 2 < niter) ? ((it + 2) << 5) : 0;
        ISSUE(knext, ii);
        asm volatile("s_waitcnt vmcnt(8)" ::: "memory");
        asm volatile("s_barrier" ::: "memory");

        const unsigned short* Ah = As + ci * 4096;
        const unsigned short* Bh = Bs + ci * 4096;
        short8 af[4], bfr[4];
        #pragma unroll
        for (int i = 0; i < 4; ++i) {
            const int row = wm + 16 * i + l16;
            af[i] = *(const short8*)&Ah[row * 32 + ((quad * 8) ^ swz8(row))];
        }
        #pragma unroll
        for (int j = 0; j < 4; ++j) {
            const int row = wn + 16 * j + l16;
            bfr[j] = *(const short8*)&Bh[row * 32 + ((quad * 8) ^ swz8(row))];
        }
        #pragma unroll
        for (int i = 0; i < 4; ++i)
            #pragma unroll
            for (int j = 0; j < 4; ++j)
                acc[i][j] = __builtin_amdgcn_mfma_f32_16x16x32_bf16(af[i], bfr[j], acc[i][j], 0, 0, 0);

        asm volatile("s_barrier" ::: "memory");
        ci = (ci == 2) ? 0 : ci + 1;
        ii = (ii == 2) ? 0 : ii + 1;
    }
    asm volatile("s_waitcnt vmcnt(0)" ::: "memory");
    #undef ISSUE
}

#define DECL_TILE_IDX() \
    const int lane = threadIdx.x & 63; \
    const int wave = threadIdx.x >> 6; \
    const int quad = lane >> 4; \
    const int l16  = lane & 15; \
    const int wm   = (wave >> 1) << 6; \
    const int wn   = (wave & 1) << 6;

// ---- m: Mt partials, k-split into 4 chunks of 256 (grid 256 = 1/CU). ----
__global__ __launch_bounds__(256, 3) void m_kernel(
    const unsigned short* __restrict__ WkT, const unsigned short* __restrict__ WqT,
    float* __restrict__ Mtf)
{
    __shared__ __align__(16) unsigned short As[3 * 128 * 32];
    __shared__ __align__(16) unsigned short Bs[3 * 128 * 32];
    const int idx = blockIdx.x;          // 0..255
    const int kc  = idx >> 6;            // k-chunk 0..3
    const int t   = idx & 63;
    const int m0  = (t >> 3) << 7;
    const int n0  = (t & 7) << 7;

    float4v acc[4][4];
    #pragma unroll
    for (int i = 0; i < 4; ++i)
        #pragma unroll
        for (int j = 0; j < 4; ++j)
            acc[i][j] = float4v{0.f, 0.f, 0.f, 0.f};

    gemm_core(WkT + kc * 256, WqT + kc * 256, EMB, EMB, m0, n0, 256, As, Bs, acc);

    float* dst = Mtf + (size_t)kc * 1024 * 1024;
    DECL_TILE_IDX();
    #pragma unroll
    for (int i = 0; i < 4; ++i)
        #pragma unroll
        for (int j = 0; j < 4; ++j)
            #pragma unroll
            for (int rr = 0; rr < 4; ++rr) {
                const int row = m0 + wm + 16 * i + quad * 4 + rr;
                const int col = n0 + wn + 16 * j + l16;
                dst[(size_t)row * EMB + col] = acc[i][j][rr];
            }
}

// ---- mc: Mt = bf16( (slab0+slab1+slab2+slab3) * 1/sqrt(A) ) ----
__global__ __launch_bounds__(256) void mc_kernel(
    const float* __restrict__ Mtf, unsigned short* __restrict__ Mt)
{
    const int base = (blockIdx.x * 256 + threadIdx.x) * 16;
    #pragma unroll
    for (int u = 0; u < 4; ++u) {
        const int i = base + u * 4;
        float4v s = *(const float4v*)(Mtf + i);
        s = s + *(const float4v*)(Mtf + 1048576 + i);
        s = s + *(const float4v*)(Mtf + 2097152 + i);
        s = s + *(const float4v*)(Mtf + 3145728 + i);
        s = s * 0.03125f;                // 1/sqrt(1024) folded here
        uint2 p = pack4(s);
        *(uint2*)(Mt + i) = p;
    }
}

// ---- qv: 256x256 tile, 512 threads (8 waves, 2Mx4N), BK=32, 3-stage 96KB,
// grid 256 = 1 block/CU. Per K32 iter: one buf-ready barrier, all 12
// ds_reads clustered (compiler emits partial lgkmcnt so af[4..7] fly under
// MFMA-A), ISSUE_QB between MFMA clusters, one end barrier. Mid-barrier
// removed (phases only READ buf ci; staging writes buf ci+2 — no hazard).
// Counted vmcnt(6) retires exactly tile it; wrapped dummy issues at tail. ----
__global__ __launch_bounds__(512, 2) void qv_kernel(
    const unsigned short* __restrict__ Xb, const unsigned short* __restrict__ Mt,
    const unsigned short* __restrict__ Wvb,
    unsigned short* __restrict__ Qpb, unsigned short* __restrict__ Vtb)
{
    __shared__ __align__(16) unsigned short LDS[49152];   // 96 KiB
    unsigned short* As = LDS;             // 3 bufs x 8192 shorts (256x32)
    unsigned short* Bs = LDS + 24576;

    const int idx  = blockIdx.x;                  // 0..255
    const int mt   = ((idx & 7) << 2) | ((idx >> 3) & 3);  // XCD-chunked m-tile
    const int slot = idx >> 5;                    // 0..7 = z*4 + n-tile
    const int z    = slot >> 2;
    const int n0   = (slot & 3) << 8;
    const int m0   = mt << 8;
    const unsigned short* B = z ? Wvb : Mt;

    const int tid  = threadIdx.x;                 // 0..511
    const int lane = tid & 63;
    const int wave = tid >> 6;                    // 0..7
    const int quad = lane >> 4;
    const int l16  = lane & 15;
    const int wm   = (wave >> 2) << 7;            // 0 / 128
    const int wn   = (wave & 3) << 6;             // 0,64,128,192

    // staging geometry: rows (tid>>2), 16B col slot (tid&3), source-swizzled
    const int srow = tid >> 2;                    // 0..127
    const int c8   = ((tid & 3) << 3) ^ swz8(srow);

    const unsigned short* Ag0 = Xb + (size_t)(m0 + srow) * EMB + c8;
    const unsigned short* Ag1 = Ag0 + (size_t)128 * EMB;
    const unsigned short* Bg0 = B  + (size_t)(n0 + srow) * EMB + c8;
    const unsigned short* Bg1 = Bg0 + (size_t)128 * EMB;
    unsigned short* Al = As + tid * 8;            // linear LDS dest
    unsigned short* Bl = Bs + tid * 8;

    #define ISSUE_QA(t, st) do { \
        gload16(Ag0 + (t) * 32, Al + (st) * 8192); \
        gload16(Ag1 + (t) * 32, Al + (st) * 8192 + 4096); \
    } while (0)
    #define ISSUE_QB(t, st) do { \
        gload16(Bg0 + (t) * 32, Bl + (st) * 8192); \
        gload16(Bg1 + (t) * 32, Bl + (st) * 8192 + 4096); \
    } while (0)

    float4v acc[8][4];
    #pragma unroll
    for (int i = 0; i < 8; ++i)
        #pragma unroll
        for (int j = 0; j < 4; ++j)
            acc[i][j] = float4v{0.f, 0.f, 0.f, 0.f};

    ISSUE_QA(0, 0); ISSUE_QB(0, 0);
    ISSUE_QA(1, 1); ISSUE_QB(1, 1);

    int ci = 0, ii = 2;
    for (int it = 0; it < 32; ++it) {
        const int tn = (it + 2 < 32) ? (it + 2) : 0;   // wrapped dummy at tail
        const unsigned short* Ah = As + ci * 8192;
        const unsigned short* Bh = Bs + ci * 8192;

        ISSUE_QA(tn, ii);
        asm volatile("s_waitcnt vmcnt(6)" ::: "memory");   // tile `it` landed
        asm volatile("s_barrier" ::: "memory");

        short8 af[8], bfr[4];
        #pragma unroll
        for (int i = 0; i < 4; ++i) {
            const int row = wm + 16 * i + l16;
            af[i] = *(const short8*)&Ah[row * 32 + ((quad * 8) ^ swz8(row))];
        }
        #pragma unroll
        for (int j = 0; j < 4; ++j) {
            const int row = wn + 16 * j + l16;
            bfr[j] = *(const short8*)&Bh[row * 32 + ((quad * 8) ^ swz8(row))];
        }
        #pragma unroll
        for (int i = 0; i < 4; ++i) {
            const int row = wm + 64 + 16 * i + l16;
            af[4 + i] = *(const short8*)&Ah[row * 32 + ((quad * 8) ^ swz8(row))];
        }

        // ---- MFMA cluster A: acc rows wm+0..63 ----
        __builtin_amdgcn_s_setprio(1);
        #pragma unroll
        for (int i = 0; i < 4; ++i)
            #pragma unroll
            for (int j = 0; j < 4; ++j)
                acc[i][j] = __builtin_amdgcn_mfma_f32_16x16x32_bf16(af[i], bfr[j], acc[i][j], 0, 0, 0);
        __builtin_amdgcn_s_setprio(0);

        ISSUE_QB(tn, ii);

        // ---- MFMA cluster B: acc rows wm+64..127 (B frags reused in regs) ----
        __builtin_amdgcn_s_setprio(1);
        #pragma unroll
        for (int i = 0; i < 4; ++i)
            #pragma unroll
            for (int j = 0; j < 4; ++j)
                acc[i + 4][j] = __builtin_amdgcn_mfma_f32_16x16x32_bf16(af[4 + i], bfr[j], acc[i + 4][j], 0, 0, 0);
        __builtin_amdgcn_s_setprio(0);

        asm volatile("s_barrier" ::: "memory");
        ci = (ci == 2) ? 0 : ci + 1;
        ii = (ii == 2) ? 0 : ii + 1;
    }
    asm volatile("s_waitcnt vmcnt(0)" ::: "memory");
    #undef ISSUE_QA
    #undef ISSUE_QB

    if (z == 0) {
        #pragma unroll
        for (int i = 0; i < 8; ++i)
            #pragma unroll
            for (int j = 0; j < 4; ++j)
                #pragma unroll
                for (int rr = 0; rr < 4; ++rr) {
                    const int row = m0 + wm + ((i & 3) << 4) + ((i >> 2) << 6) + quad * 4 + rr;
                    const int col = n0 + wn + 16 * j + l16;
                    Qpb[(size_t)row * ADIM + col] = f2bf(acc[i][j][rr]);
                }
    } else {
        // V -> Vtb transpose, two 128-q passes through LDS.
        // T layout: [acol 0..255][qloc 0..127], q-stride 136 shorts.
        const int bb = m0 >> 11;
        const int l0 = m0 & (SEQ - 1);
        #pragma unroll
        for (int h = 0; h < 2; ++h) {
            __syncthreads();
            if ((wm >> 7) == h) {
                #pragma unroll
                for (int i = 0; i < 8; ++i)
                    #pragma unroll
                    for (int j = 0; j < 4; ++j) {
                        const int qloc = ((i & 3) << 4) + ((i >> 2) << 6) + quad * 4;  // 0..124
                        const int acol = wn + 16 * j + l16;                            // 0..255
                        uint2 w;
                        w.x = (unsigned)f2bf(acc[i][j][0]) | ((unsigned)f2bf(acc[i][j][1]) << 16);
                        w.y = (unsigned)f2bf(acc[i][j][2]) | ((unsigned)f2bf(acc[i][j][3]) << 16);
                        *(uint2*)&LDS[acol * 136 + qloc] = w;    // 8B store, 8B-aligned
                    }
            }
            __syncthreads();
            // thread t owns (acol = t>>1, 64-q chunk (t&1)): 128B burst
            const int acol = tid >> 1;
            const int qh   = (tid & 1) << 6;
            unsigned short* dst = Vtb + (((size_t)(bb * ADIM + n0 + acol)) << 11)
                                      + l0 + h * 128 + qh;
            #pragma unroll
            for (int u = 0; u < 8; ++u)
                *(uint4*)(dst + u * 8) = *(const uint4*)&LDS[acol * 136 + qh + u * 8];
        }
    }
}

// ---- E = exp(Q' Xb^T) (scale pre-folded into Mt), causal, + rowsum atomics ----
__global__ __launch_bounds__(256, 3) void s_kernel(
    const unsigned short* __restrict__ Qpb, const unsigned short* __restrict__ Xb,
    unsigned short* __restrict__ E, float* __restrict__ rowsum)
{
    const int idx = blockIdx.x;
    const int b   = idx & 3;
    const int tri = idx >> 2;
    int qt = 0;
    while (((qt + 1) * (qt + 2)) / 2 <= tri) ++qt;
    const int kt = tri - (qt * (qt + 1)) / 2;
    const int q0 = qt << 7;
    const int k0 = kt << 7;

    __shared__ __align__(16) unsigned short As[3 * 128 * 32];
    __shared__ __align__(16) unsigned short Bs[3 * 128 * 32];

    float4v acc[4][4];
    #pragma unroll
    for (int i = 0; i < 4; ++i)
        #pragma unroll
        for (int j = 0; j < 4; ++j)
            acc[i][j] = float4v{0.f, 0.f, 0.f, 0.f};

    gemm_core(Qpb + (size_t)b * SEQ * ADIM, Xb + (size_t)b * SEQ * EMB,
              ADIM, EMB, q0, k0, EMB, As, Bs, acc);

    unsigned short* Eb = E + (size_t)b * SEQ * SEQ;
    float* rsb = rowsum + (size_t)b * SEQ;
    DECL_TILE_IDX();
    #pragma unroll
    for (int i = 0; i < 4; ++i)
        #pragma unroll
        for (int rr = 0; rr < 4; ++rr) {
            const int row = q0 + wm + 16 * i + quad * 4 + rr;
            float s = 0.f;
            #pragma unroll
            for (int j = 0; j < 4; ++j) {
                const int col = k0 + wn + 16 * j + l16;
                float e = (col <= row) ? __expf(acc[i][j][rr]) : 0.f;
                s += e;
                Eb[(size_t)row * SEQ + col] = f2bf(e);
            }
            s += __shfl_xor(s, 1);
            s += __shfl_xor(s, 2);
            s += __shfl_xor(s, 4);
            s += __shfl_xor(s, 8);
            if (l16 == 0) atomicAdd(&rsb[row], s);
        }
}

// ---- O = (E V) / rowsum. Balanced pairing: blocks c and c+256 land on the
// same CU (round-robin %8 XCD, /8 %32 CU both match) and their t sum to 15,
// so every CU carries a constant 17 t-units. ----
__global__ __launch_bounds__(256, 3) void pv_kernel(
    const unsigned short* __restrict__ E, const unsigned short* __restrict__ Vtb,
    const float* __restrict__ rowsum, float* __restrict__ out)
{
    const int idx = blockIdx.x;
    const int t   = (idx < 256) ? (15 - (idx >> 5)) : ((idx - 256) >> 5);
    const int rem = idx & 31;
    const int b   = rem >> 3;
    const int a0  = (rem & 7) << 7;
    const int q0  = t << 7;

    __shared__ __align__(16) unsigned short As[3 * 128 * 32];
    __shared__ __align__(16) unsigned short Bs[3 * 128 * 32];

    float4v acc[4][4];
    #pragma unroll
    for (int i = 0; i < 4; ++i)
        #pragma unroll
        for (int j = 0; j < 4; ++j)
            acc[i][j] = float4v{0.f, 0.f, 0.f, 0.f};

    gemm_core(E + (size_t)b * SEQ * SEQ, Vtb + (size_t)b * ADIM * SEQ,
              SEQ, SEQ, q0, a0, q0 + 128, As, Bs, acc);

    float* ob = out + (size_t)b * SEQ * ADIM;
    const float* rsb = rowsum + (size_t)b * SEQ;
    DECL_TILE_IDX();
    #pragma unroll
    for (int i = 0; i < 4; ++i)
        #pragma unroll
        for (int rr = 0; rr < 4; ++rr) {
            const int row = q0 + wm + 16 * i + quad * 4 + rr;
            const float inv = 1.0f / rsb[row];
            #pragma unroll
            for (int j = 0; j < 4; ++j) {
                const int col = a0 + wn + 16 * j + l16;
                ob[(size_t)row * ADIM + col] = acc[i][j][rr] * inv;
            }
        }
}

extern "C" void kernel_launch(void* const* d_in, const int* in_sizes, int n_in,
                              void* d_out, int out_size, void* d_ws, size_t ws_size,
                              hipStream_t stream)
{
    // setup_inputs order: embedded, W_K, W_Q, W_V
    const float* X  = (const float*)d_in[0];
    const float* Wk = (const float*)d_in[1];
    const float* Wq = (const float*)d_in[2];
    const float* Wv = (const float*)d_in[3];
    float* out = (float*)d_out;

    const size_t MB = 1024 * 1024;
    char* ws = (char*)d_ws;
    unsigned short* Xb  = (unsigned short*)(ws);             // [0,16) MB
    unsigned short* Wvb = (unsigned short*)(ws + 16 * MB);   // [16,18)
    unsigned short* WqT = (unsigned short*)(ws + 18 * MB);   // [18,20)
    unsigned short* WkT = (unsigned short*)(ws + 20 * MB);   // [20,22)
    unsigned short* Mt  = (unsigned short*)(ws + 22 * MB);   // [22,24)
    unsigned short* Qpb = (unsigned short*)(ws + 24 * MB);   // [24,40)
    unsigned short* E   = (unsigned short*)(ws + 40 * MB);   // [40,72)
    unsigned short* Vtb = (unsigned short*)(ws + 72 * MB);   // [72,88)
    float*          rowsum = (float*)(ws + 88 * MB);         // 32 KB
    // Mtf slabs (16 MB fp32) reuse the E region: dead before s_kernel writes E.
    float*          Mtf = (float*)(ws + 40 * MB);

    hipLaunchKernelGGL(prep_kernel, dim3(5128), dim3(256), 0, stream,
                       X, Wv, Wq, Wk, Xb, Wvb, WqT, WkT, rowsum);
    hipLaunchKernelGGL(m_kernel, dim3(256), dim3(256), 0, stream, WkT, WqT, Mtf);
    hipLaunchKernelGGL(mc_kernel, dim3(256), dim3(256), 0, stream, Mtf, Mt);
    hipLaunchKernelGGL(qv_kernel, dim3(256), dim3(512), 0, stream,
                       Xb, Mt, Wvb, Qpb, Vtb);
    hipLaunchKernelGGL(s_kernel, dim3(4 * 136), dim3(256), 0, stream, Qpb, Xb, E, rowsum);
    hipLaunchKernelGGL(pv_kernel, dim3(512), dim3(256), 0, stream, E, Vtb, rowsum, out);
}

// Round 11
// 223.540 us; speedup vs baseline: 1.0024x; 1.0024x over previous
//
#include <hip/hip_runtime.h>
#include <hip/hip_bf16.h>
#include <stdint.h>

#define BATCH 4
#define SEQ   2048
#define EMB   1024
#define ADIM  1024

typedef __attribute__((ext_vector_type(8))) short  short8;
typedef __attribute__((ext_vector_type(4))) float  float4v;

static __device__ __forceinline__ unsigned short f2bf(float f) {
    unsigned int u = __float_as_uint(f);
    u += 0x7FFFu + ((u >> 16) & 1u);   // RNE (finite inputs)
    return (unsigned short)(u >> 16);
}

static __device__ __forceinline__ uint2 pack4(float4v v) {
    uint2 r;
    r.x = (unsigned)f2bf(v.x) | ((unsigned)f2bf(v.y) << 16);
    r.y = (unsigned)f2bf(v.z) | ((unsigned)f2bf(v.w) << 16);
    return r;
}

// async global->LDS, 16B per lane. LDS dest is wave-uniform base + lane*16.
static __device__ __forceinline__ void gload16(const void* g, void* l) {
    __builtin_amdgcn_global_load_lds(
        (const __attribute__((address_space(1))) void*)g,
        (__attribute__((address_space(3))) void*)l, 16, 0, 0);
}

// bank swizzle for 64B LDS rows (element-unit XOR for 8-el/16B accesses)
static __device__ __forceinline__ int swz8(int row) { return ((row >> 1) & 3) << 3; }

// ---- fused prep: X->Xb, Wv->Wvb, zero rowsum, transpose-convert Wq/Wk ----
__global__ __launch_bounds__(256) void prep_kernel(
    const float* __restrict__ X,  const float* __restrict__ Wv,
    const float* __restrict__ Wq, const float* __restrict__ Wk,
    unsigned short* __restrict__ Xb, unsigned short* __restrict__ Wvb,
    unsigned short* __restrict__ WqT, unsigned short* __restrict__ WkT,
    float* __restrict__ rowsum)
{
    __shared__ unsigned short T[64][72];
    const int bI = blockIdx.x;
    if (bI < 4608) {              // straight convert
        const float* src; unsigned short* dst; int off;
        if (bI < 4096) { src = X;  dst = Xb;  off = bI; }
        else           { src = Wv; dst = Wvb; off = bI - 4096; }
        const int i = (off * 256 + threadIdx.x) * 8;
        float4v a = *(const float4v*)(src + i);
        float4v b = *(const float4v*)(src + i + 4);
        uint2 pa = pack4(a), pb = pack4(b);
        uint4 o; o.x = pa.x; o.y = pa.y; o.z = pb.x; o.w = pb.y;
        *(uint4*)(dst + i) = o;
        return;
    }
    if (bI < 4616) {              // zero 32 KB rowsum
        const int i = ((bI - 4608) * 256 + threadIdx.x) * 4;
        *(float4v*)(rowsum + i) = float4v{0.f, 0.f, 0.f, 0.f};
        return;
    }
    // transpose-convert: W fp32 [a][e] -> WT bf16 [e][a], 64x64 tiles
    const int z    = (bI - 4616) >> 8;     // 0: Wq, 1: Wk
    const int tile = (bI - 4616) & 255;
    const int ti = tile >> 4;              // a-tile
    const int tj = tile & 15;              // e-tile
    const float* W = z ? Wk : Wq;
    unsigned short* WT = z ? WkT : WqT;
    const int t  = threadIdx.x;
    const int r  = t >> 2;                 // 0..63
    const int c  = (t & 3) << 4;           // 0,16,32,48

    const float* src = W + (size_t)(ti * 64 + r) * EMB + tj * 64 + c;
    #pragma unroll
    for (int u = 0; u < 4; ++u) {
        float4v v = *(const float4v*)(src + 4 * u);
        uint2 p = pack4(v);
        *(uint2*)&T[r][c + 4 * u] = p;
    }
    __syncthreads();
    unsigned short tmp[16];
    #pragma unroll
    for (int u = 0; u < 16; ++u) tmp[u] = T[c + u][r];
    unsigned short* dst = WT + (size_t)(tj * 64 + r) * EMB + ti * 64 + c;
    *(uint4*)(dst)     = *(uint4*)&tmp[0];
    *(uint4*)(dst + 8) = *(uint4*)&tmp[8];
}

// ---- 128x128 core: 3-stage pipeline, BK=32/stage, vmcnt(8), raw barriers.
// LDS bank-swizzled both sides (source-swizzled gload + XOR'd ds_read). ----
static __device__ __forceinline__ void gemm_core(
    const unsigned short* __restrict__ A, const unsigned short* __restrict__ B,
    int lda, int ldb, int m0, int n0, int klen,
    unsigned short* As, unsigned short* Bs, float4v acc[4][4])
{
    const int tid  = threadIdx.x;
    const int r    = tid >> 2;
    const int c8   = ((tid & 3) << 3) ^ swz8(tid >> 2);   // source-swizzled
    const int lane = tid & 63;
    const int wave = tid >> 6;
    const int quad = lane >> 4;
    const int l16  = lane & 15;
    const int wm   = (wave >> 1) << 6;
    const int wn   = (wave & 1) << 6;

    const unsigned short* Ag = A + (size_t)(m0 + r) * lda + c8;
    const unsigned short* Bg = B + (size_t)(n0 + r) * ldb + c8;
    unsigned short* Al = As + tid * 8;
    unsigned short* Bl = Bs + tid * 8;
    const int niter = klen >> 5;

    #define ISSUE(k0, st) do { \
        unsigned short* al_ = Al + (st) * 4096; \
        unsigned short* bl_ = Bl + (st) * 4096; \
        gload16(Ag + (k0),                    al_); \
        gload16(Ag + (k0) + (size_t)64 * lda, al_ + 2048); \
        gload16(Bg + (k0),                    bl_); \
        gload16(Bg + (k0) + (size_t)64 * ldb, bl_ + 2048); \
    } while (0)

    ISSUE(0, 0);
    ISSUE(32, 1);

    int ci = 0, ii = 2;
    for (int it = 0; it < niter; ++it) {
        const int knext = (it + 2 < niter) ? ((it + 2) << 5) : 0;
        ISSUE(knext, ii);
        asm volatile("s_waitcnt vmcnt(8)" ::: "memory");
        asm volatile("s_barrier" ::: "memory");

        const unsigned short* Ah = As + ci * 4096;
        const unsigned short* Bh = Bs + ci * 4096;
        short8 af[4], bfr[4];
        #pragma unroll
        for (int i = 0; i < 4; ++i) {
            const int row = wm + 16 * i + l16;
            af[i] = *(const short8*)&Ah[row * 32 + ((quad * 8) ^ swz8(row))];
        }
        #pragma unroll
        for (int j = 0; j < 4; ++j) {
            const int row = wn + 16 * j + l16;
            bfr[j] = *(const short8*)&Bh[row * 32 + ((quad * 8) ^ swz8(row))];
        }
        #pragma unroll
        for (int i = 0; i < 4; ++i)
            #pragma unroll
            for (int j = 0; j < 4; ++j)
                acc[i][j] = __builtin_amdgcn_mfma_f32_16x16x32_bf16(af[i], bfr[j], acc[i][j], 0, 0, 0);

        asm volatile("s_barrier" ::: "memory");
        ci = (ci == 2) ? 0 : ci + 1;
        ii = (ii == 2) ? 0 : ii + 1;
    }
    asm volatile("s_waitcnt vmcnt(0)" ::: "memory");
    #undef ISSUE
}

#define DECL_TILE_IDX() \
    const int lane = threadIdx.x & 63; \
    const int wave = threadIdx.x >> 6; \
    const int quad = lane >> 4; \
    const int l16  = lane & 15; \
    const int wm   = (wave >> 1) << 6; \
    const int wn   = (wave & 1) << 6;

// ---- m: Mt partials, k-split into 4 chunks of 256 (grid 256 = 1/CU). ----
__global__ __launch_bounds__(256, 3) void m_kernel(
    const unsigned short* __restrict__ WkT, const unsigned short* __restrict__ WqT,
    float* __restrict__ Mtf)
{
    __shared__ __align__(16) unsigned short As[3 * 128 * 32];
    __shared__ __align__(16) unsigned short Bs[3 * 128 * 32];
    const int idx = blockIdx.x;          // 0..255
    const int kc  = idx >> 6;            // k-chunk 0..3
    const int t   = idx & 63;
    const int m0  = (t >> 3) << 7;
    const int n0  = (t & 7) << 7;

    float4v acc[4][4];
    #pragma unroll
    for (int i = 0; i < 4; ++i)
        #pragma unroll
        for (int j = 0; j < 4; ++j)
            acc[i][j] = float4v{0.f, 0.f, 0.f, 0.f};

    gemm_core(WkT + kc * 256, WqT + kc * 256, EMB, EMB, m0, n0, 256, As, Bs, acc);

    float* dst = Mtf + (size_t)kc * 1024 * 1024;
    DECL_TILE_IDX();
    #pragma unroll
    for (int i = 0; i < 4; ++i)
        #pragma unroll
        for (int j = 0; j < 4; ++j)
            #pragma unroll
            for (int rr = 0; rr < 4; ++rr) {
                const int row = m0 + wm + 16 * i + quad * 4 + rr;
                const int col = n0 + wn + 16 * j + l16;
                dst[(size_t)row * EMB + col] = acc[i][j][rr];
            }
}

// ---- mc: Mt = bf16( (slab0+slab1+slab2+slab3) * 1/sqrt(A) ) ----
__global__ __launch_bounds__(256) void mc_kernel(
    const float* __restrict__ Mtf, unsigned short* __restrict__ Mt)
{
    const int base = (blockIdx.x * 256 + threadIdx.x) * 16;
    #pragma unroll
    for (int u = 0; u < 4; ++u) {
        const int i = base + u * 4;
        float4v s = *(const float4v*)(Mtf + i);
        s = s + *(const float4v*)(Mtf + 1048576 + i);
        s = s + *(const float4v*)(Mtf + 2097152 + i);
        s = s + *(const float4v*)(Mtf + 3145728 + i);
        s = s * 0.03125f;                // 1/sqrt(1024) folded here
        uint2 p = pack4(s);
        *(uint2*)(Mt + i) = p;
    }
}

// ---- qv: 256x256 tile, 512 threads (8 waves, 2Mx4N), BK=64, 2-stage 128KB,
// grid 256 = 1 block/CU. 16 K64 iters (half the sync sequences of BK=32).
// Per iter: issue next tile (8 gloads), counted vmcnt(8) retires exactly
// tile `it`, barrier, 2 k-halves x 32 MFMA under setprio, end barrier.
// 128B LDS rows with full 8-granule XOR swizzle (granule ^= row&7), applied
// on BOTH sides (pre-swizzled global slot + swizzled ds_read). ----
__global__ __launch_bounds__(512, 1) void qv_kernel(
    const unsigned short* __restrict__ Xb, const unsigned short* __restrict__ Mt,
    const unsigned short* __restrict__ Wvb,
    unsigned short* __restrict__ Qpb, unsigned short* __restrict__ Vtb)
{
    __shared__ __align__(16) unsigned short LDS[65536];   // 128 KiB
    unsigned short* As = LDS;             // 2 stages x 16384 shorts (256x64)
    unsigned short* Bs = LDS + 32768;

    const int idx  = blockIdx.x;                  // 0..255
    const int mt   = ((idx & 7) << 2) | ((idx >> 3) & 3);  // XCD-chunked m-tile
    const int slot = idx >> 5;                    // 0..7 = z*4 + n-tile
    const int z    = slot >> 2;
    const int n0   = (slot & 3) << 8;
    const int m0   = mt << 8;
    const unsigned short* B = z ? Wvb : Mt;

    const int tid  = threadIdx.x;                 // 0..511
    const int lane = tid & 63;
    const int wave = tid >> 6;                    // 0..7
    const int quad = lane >> 4;
    const int l16  = lane & 15;
    const int wm   = (wave >> 2) << 7;            // 0 / 128
    const int wn   = (wave & 3) << 6;             // 0,64,128,192

    // staging geometry: per load u (0..3): row = 64u + (tid>>3), LDS granule
    // tid&7 receives global 16B-slot (tid&7) ^ (row&7). row&7 == (tid>>3)&7.
    const int r8 = tid >> 3;                      // 0..63
    const int sg = (tid & 7) ^ (r8 & 7);          // pre-swizzled global slot

    const unsigned short* Ag = Xb + (size_t)(m0 + r8) * EMB + sg * 8;
    const unsigned short* Bg = B  + (size_t)(n0 + r8) * EMB + sg * 8;
    unsigned short* Al = As + tid * 8;            // + u*4096 shorts per load
    unsigned short* Bl = Bs + tid * 8;

    // 8 loads per tile: 4 A-rows-blocks + 4 B-rows-blocks (64 rows each)
    #define ISSUE_T(t64, st) do { \
        const size_t ko_ = (size_t)(t64) * 64; \
        gload16(Ag + ko_,                       Al + (st) * 16384); \
        gload16(Ag + ko_ + (size_t)64  * EMB,   Al + (st) * 16384 + 4096); \
        gload16(Ag + ko_ + (size_t)128 * EMB,   Al + (st) * 16384 + 8192); \
        gload16(Ag + ko_ + (size_t)192 * EMB,   Al + (st) * 16384 + 12288); \
        gload16(Bg + ko_,                       Bl + (st) * 16384); \
        gload16(Bg + ko_ + (size_t)64  * EMB,   Bl + (st) * 16384 + 4096); \
        gload16(Bg + ko_ + (size_t)128 * EMB,   Bl + (st) * 16384 + 8192); \
        gload16(Bg + ko_ + (size_t)192 * EMB,   Bl + (st) * 16384 + 12288); \
    } while (0)

    float4v acc[8][4];
    #pragma unroll
    for (int i = 0; i < 8; ++i)
        #pragma unroll
        for (int j = 0; j < 4; ++j)
            acc[i][j] = float4v{0.f, 0.f, 0.f, 0.f};

    ISSUE_T(0, 0);

    for (int it = 0; it < 16; ++it) {
        const int tn = (it + 1 < 16) ? (it + 1) : 0;   // wrapped dummy at tail
        ISSUE_T(tn, (it + 1) & 1);
        asm volatile("s_waitcnt vmcnt(8)" ::: "memory");   // tile `it` landed
        asm volatile("s_barrier" ::: "memory");

        const unsigned short* Ah = As + (it & 1) * 16384;
        const unsigned short* Bh = Bs + (it & 1) * 16384;

        // ---- k-half 0: granules quad ----
        {
            short8 af[8], bfr[4];
            #pragma unroll
            for (int i = 0; i < 8; ++i) {
                const int row = wm + 16 * i + l16;
                af[i] = *(const short8*)&Ah[row * 64 + ((quad ^ (row & 7)) << 3)];
            }
            #pragma unroll
            for (int j = 0; j < 4; ++j) {
                const int row = wn + 16 * j + l16;
                bfr[j] = *(const short8*)&Bh[row * 64 + ((quad ^ (row & 7)) << 3)];
            }
            __builtin_amdgcn_s_setprio(1);
            #pragma unroll
            for (int i = 0; i < 8; ++i)
                #pragma unroll
                for (int j = 0; j < 4; ++j)
                    acc[i][j] = __builtin_amdgcn_mfma_f32_16x16x32_bf16(af[i], bfr[j], acc[i][j], 0, 0, 0);
            __builtin_amdgcn_s_setprio(0);
        }
        // ---- k-half 1: granules 4+quad ----
        {
            short8 af[8], bfr[4];
            #pragma unroll
            for (int i = 0; i < 8; ++i) {
                const int row = wm + 16 * i + l16;
                af[i] = *(const short8*)&Ah[row * 64 + (((4 + quad) ^ (row & 7)) << 3)];
            }
            #pragma unroll
            for (int j = 0; j < 4; ++j) {
                const int row = wn + 16 * j + l16;
                bfr[j] = *(const short8*)&Bh[row * 64 + (((4 + quad) ^ (row & 7)) << 3)];
            }
            __builtin_amdgcn_s_setprio(1);
            #pragma unroll
            for (int i = 0; i < 8; ++i)
                #pragma unroll
                for (int j = 0; j < 4; ++j)
                    acc[i][j] = __builtin_amdgcn_mfma_f32_16x16x32_bf16(af[i], bfr[j], acc[i][j], 0, 0, 0);
            __builtin_amdgcn_s_setprio(0);
        }

        asm volatile("s_barrier" ::: "memory");
    }
    asm volatile("s_waitcnt vmcnt(0)" ::: "memory");
    #undef ISSUE_T

    if (z == 0) {
        #pragma unroll
        for (int i = 0; i < 8; ++i)
            #pragma unroll
            for (int j = 0; j < 4; ++j)
                #pragma unroll
                for (int rr = 0; rr < 4; ++rr) {
                    const int row = m0 + wm + 16 * i + quad * 4 + rr;
                    const int col = n0 + wn + 16 * j + l16;
                    Qpb[(size_t)row * ADIM + col] = f2bf(acc[i][j][rr]);
                }
    } else {
        // V -> Vtb transpose, two 128-q passes through LDS.
        // T layout: [acol 0..255][qloc 0..127], q-stride 136 shorts.
        const int bb = m0 >> 11;
        const int l0 = m0 & (SEQ - 1);
        #pragma unroll
        for (int h = 0; h < 2; ++h) {
            __syncthreads();
            if ((wm >> 7) == h) {
                #pragma unroll
                for (int i = 0; i < 8; ++i)
                    #pragma unroll
                    for (int j = 0; j < 4; ++j) {
                        const int qloc = 16 * i + quad * 4;      // 0..124
                        const int acol = wn + 16 * j + l16;      // 0..255
                        uint2 w;
                        w.x = (unsigned)f2bf(acc[i][j][0]) | ((unsigned)f2bf(acc[i][j][1]) << 16);
                        w.y = (unsigned)f2bf(acc[i][j][2]) | ((unsigned)f2bf(acc[i][j][3]) << 16);
                        *(uint2*)&LDS[acol * 136 + qloc] = w;    // 8B store, 8B-aligned
                    }
            }
            __syncthreads();
            // thread t owns (acol = t>>1, 64-q chunk (t&1)): 128B burst
            const int acol = tid >> 1;
            const int qh   = (tid & 1) << 6;
            unsigned short* dst = Vtb + (((size_t)(bb * ADIM + n0 + acol)) << 11)
                                      + l0 + h * 128 + qh;
            #pragma unroll
            for (int u = 0; u < 8; ++u)
                *(uint4*)(dst + u * 8) = *(const uint4*)&LDS[acol * 136 + qh + u * 8];
        }
    }
}

// ---- E = exp(Q' Xb^T) (scale pre-folded into Mt), causal, + rowsum atomics ----
__global__ __launch_bounds__(256, 3) void s_kernel(
    const unsigned short* __restrict__ Qpb, const unsigned short* __restrict__ Xb,
    unsigned short* __restrict__ E, float* __restrict__ rowsum)
{
    const int idx = blockIdx.x;
    const int b   = idx & 3;
    const int tri = idx >> 2;
    int qt = 0;
    while (((qt + 1) * (qt + 2)) / 2 <= tri) ++qt;
    const int kt = tri - (qt * (qt + 1)) / 2;
    const int q0 = qt << 7;
    const int k0 = kt << 7;

    __shared__ __align__(16) unsigned short As[3 * 128 * 32];
    __shared__ __align__(16) unsigned short Bs[3 * 128 * 32];

    float4v acc[4][4];
    #pragma unroll
    for (int i = 0; i < 4; ++i)
        #pragma unroll
        for (int j = 0; j < 4; ++j)
            acc[i][j] = float4v{0.f, 0.f, 0.f, 0.f};

    gemm_core(Qpb + (size_t)b * SEQ * ADIM, Xb + (size_t)b * SEQ * EMB,
              ADIM, EMB, q0, k0, EMB, As, Bs, acc);

    unsigned short* Eb = E + (size_t)b * SEQ * SEQ;
    float* rsb = rowsum + (size_t)b * SEQ;
    DECL_TILE_IDX();
    #pragma unroll
    for (int i = 0; i < 4; ++i)
        #pragma unroll
        for (int rr = 0; rr < 4; ++rr) {
            const int row = q0 + wm + 16 * i + quad * 4 + rr;
            float s = 0.f;
            #pragma unroll
            for (int j = 0; j < 4; ++j) {
                const int col = k0 + wn + 16 * j + l16;
                float e = (col <= row) ? __expf(acc[i][j][rr]) : 0.f;
                s += e;
                Eb[(size_t)row * SEQ + col] = f2bf(e);
            }
            s += __shfl_xor(s, 1);
            s += __shfl_xor(s, 2);
            s += __shfl_xor(s, 4);
            s += __shfl_xor(s, 8);
            if (l16 == 0) atomicAdd(&rsb[row], s);
        }
}

// ---- O = (E V) / rowsum. Balanced pairing: blocks c and c+256 land on the
// same CU (round-robin %8 XCD, /8 %32 CU both match) and their t sum to 15,
// so every CU carries a constant 17 t-units. ----
__global__ __launch_bounds__(256, 3) void pv_kernel(
    const unsigned short* __restrict__ E, const unsigned short* __restrict__ Vtb,
    const float* __restrict__ rowsum, float* __restrict__ out)
{
    const int idx = blockIdx.x;
    const int t   = (idx < 256) ? (15 - (idx >> 5)) : ((idx - 256) >> 5);
    const int rem = idx & 31;
    const int b   = rem >> 3;
    const int a0  = (rem & 7) << 7;
    const int q0  = t << 7;

    __shared__ __align__(16) unsigned short As[3 * 128 * 32];
    __shared__ __align__(16) unsigned short Bs[3 * 128 * 32];

    float4v acc[4][4];
    #pragma unroll
    for (int i = 0; i < 4; ++i)
        #pragma unroll
        for (int j = 0; j < 4; ++j)
            acc[i][j] = float4v{0.f, 0.f, 0.f, 0.f};

    gemm_core(E + (size_t)b * SEQ * SEQ, Vtb + (size_t)b * ADIM * SEQ,
              SEQ, SEQ, q0, a0, q0 + 128, As, Bs, acc);

    float* ob = out + (size_t)b * SEQ * ADIM;
    const float* rsb = rowsum + (size_t)b * SEQ;
    DECL_TILE_IDX();
    #pragma unroll
    for (int i = 0; i < 4; ++i)
        #pragma unroll
        for (int rr = 0; rr < 4; ++rr) {
            const int row = q0 + wm + 16 * i + quad * 4 + rr;
            const float inv = 1.0f / rsb[row];
            #pragma unroll
            for (int j = 0; j < 4; ++j) {
                const int col = a0 + wn + 16 * j + l16;
                ob[(size_t)row * ADIM + col] = acc[i][j][rr] * inv;
            }
        }
}

extern "C" void kernel_launch(void* const* d_in, const int* in_sizes, int n_in,
                              void* d_out, int out_size, void* d_ws, size_t ws_size,
                              hipStream_t stream)
{
    // setup_inputs order: embedded, W_K, W_Q, W_V
    const float* X  = (const float*)d_in[0];
    const float* Wk = (const float*)d_in[1];
    const float* Wq = (const float*)d_in[2];
    const float* Wv = (const float*)d_in[3];
    float* out = (float*)d_out;

    const size_t MB = 1024 * 1024;
    char* ws = (char*)d_ws;
    unsigned short* Xb  = (unsigned short*)(ws);             // [0,16) MB
    unsigned short* Wvb = (unsigned short*)(ws + 16 * MB);   // [16,18)
    unsigned short* WqT = (unsigned short*)(ws + 18 * MB);   // [18,20)
    unsigned short* WkT = (unsigned short*)(ws + 20 * MB);   // [20,22)
    unsigned short* Mt  = (unsigned short*)(ws + 22 * MB);   // [22,24)
    unsigned short* Qpb = (unsigned short*)(ws + 24 * MB);   // [24,40)
    unsigned short* E   = (unsigned short*)(ws + 40 * MB);   // [40,72)
    unsigned short* Vtb = (unsigned short*)(ws + 72 * MB);   // [72,88)
    float*          rowsum = (float*)(ws + 88 * MB);         // 32 KB
    // Mtf slabs (16 MB fp32) reuse the E region: dead before s_kernel writes E.
    float*          Mtf = (float*)(ws + 40 * MB);

    hipLaunchKernelGGL(prep_kernel, dim3(5128), dim3(256), 0, stream,
                       X, Wv, Wq, Wk, Xb, Wvb, WqT, WkT, rowsum);
    hipLaunchKernelGGL(m_kernel, dim3(256), dim3(256), 0, stream, WkT, WqT, Mtf);
    hipLaunchKernelGGL(mc_kernel, dim3(256), dim3(256), 0, stream, Mtf, Mt);
    hipLaunchKernelGGL(qv_kernel, dim3(256), dim3(512), 0, stream,
                       Xb, Mt, Wvb, Qpb, Vtb);
    hipLaunchKernelGGL(s_kernel, dim3(4 * 136), dim3(256), 0, stream, Qpb, Xb, E, rowsum);
    hipLaunchKernelGGL(pv_kernel, dim3(512), dim3(256), 0, stream, E, Vtb, rowsum, out);
}